// Round 4
// baseline (13342.267 us; speedup 1.0000x reference)
//
#include <hip/hip_runtime.h>
#include <hip/hip_bf16.h>
#include <math.h>

static constexpr int Bn = 8192;
static constexpr int Dn = 1536;
static constexpr int Hn = 16384;
static constexpr int KTOP = 64;
static constexpr int CHUNK = 1024;          // rows per encoder/topk chunk
static constexpr double EPSD = 1e-5;

// ---- workspace byte offsets (total use < 81 MB) ----
static constexpr size_t MU_OFF  = 0;                 // float[8192]
static constexpr size_t STD_OFF = 32768;             // float[8192]
static constexpr size_t THR_OFF = 65536;             // float[8192]
static constexpr size_t CNT_OFF = 98304;             // unsigned[8192]
static constexpr size_t NNZ_OFF = 131072;            // unsigned[1]
static constexpr size_t SUM_OFF = 131200;            // double[2]
static constexpr size_t MUD_OFF = 262144;            // double[8192] (64 KB)
static constexpr size_t RID_OFF = 327680;            // double[8192] (64 KB)
static constexpr size_t IDX_OFF = (size_t)1 << 20;   // int[8192*128]   (4 MB)
static constexpr size_t VAL_OFF = (size_t)6 << 20;   // float[8192*128] (4 MB)
static constexpr size_t HB_OFF  = (size_t)16 << 20;  // float[CHUNK*16384] (64 MB)

__global__ void k_zero(unsigned* nnz, double* sums) {
    if (threadIdx.x == 0) { *nnz = 0u; sums[0] = 0.0; sums[1] = 0.0; }
}

// f64-accurate row stats: mu, rinv = 1/(std+eps) (f64) + f32 copies
__global__ __launch_bounds__(256) void k_rowstats(const float* __restrict__ x,
                                                  double* __restrict__ muD,
                                                  double* __restrict__ rinvD,
                                                  float* __restrict__ muF,
                                                  float* __restrict__ stdF) {
    const int row = blockIdx.x;
    const int tid = threadIdx.x;
    const float* xr = x + (size_t)row * Dn;
    float v[6];
#pragma unroll
    for (int i = 0; i < 6; ++i) v[i] = xr[tid + 256 * i];
    double s = 0.0;
#pragma unroll
    for (int i = 0; i < 6; ++i) s += (double)v[i];
    __shared__ double redD[4];
    __shared__ double smu;
#pragma unroll
    for (int o = 32; o > 0; o >>= 1) s += __shfl_down(s, o);
    if ((tid & 63) == 0) redD[tid >> 6] = s;
    __syncthreads();
    if (tid == 0) {
        double m = (redD[0] + redD[1] + redD[2] + redD[3]) / (double)Dn;
        smu = m;
    }
    __syncthreads();
    const double m = smu;
    double q = 0.0;
#pragma unroll
    for (int i = 0; i < 6; ++i) { double d = (double)v[i] - m; q += d * d; }
#pragma unroll
    for (int o = 32; o > 0; o >>= 1) q += __shfl_down(q, o);
    if ((tid & 63) == 0) redD[tid >> 6] = q;
    __syncthreads();
    if (tid == 0) {
        double var = (redD[0] + redD[1] + redD[2] + redD[3]) / (double)(Dn - 1);
        double sd = sqrt(var);
        muD[row] = m;
        rinvD[row] = 1.0 / (sd + EPSD);
        muF[row] = (float)m;
        stdF[row] = (float)sd;
    }
}

// W_dec (D,H) f32 -> W_decT (H,D) f32, staged in the d_out h_sparse region
__global__ __launch_bounds__(256) void k_transpose(const float* __restrict__ Wdec,
                                                   float* __restrict__ WdecT) {
    __shared__ float tile[32][33];
    const int h0 = blockIdx.x * 32;
    const int d0 = blockIdx.y * 32;
    const int tx = threadIdx.x & 31;
    const int ty = threadIdx.x >> 5; // 0..7
#pragma unroll
    for (int r = 0; r < 4; ++r) {
        int d = ty + r * 8;
        tile[d][tx] = Wdec[(size_t)(d0 + d) * Hn + h0 + tx];
    }
    __syncthreads();
#pragma unroll
    for (int r = 0; r < 4; ++r) {
        int h = ty + r * 8;
        WdecT[(size_t)(h0 + h) * Dn + d0 + tx] = tile[tx][h];
    }
}

// Encoder GEMM with f64 accumulation: h = relu((xn - pre_bias) @ Wenc^T + lat_bias)
// BM=BN=64, BK=32, 256 threads (16x16), 4x4 f64 microtile.
__global__ __launch_bounds__(256) void k_encoder(const float* __restrict__ x,
                                                 const float* __restrict__ Wenc,
                                                 const float* __restrict__ pre_bias,
                                                 const float* __restrict__ lat_bias,
                                                 const double* __restrict__ muD,
                                                 const double* __restrict__ rinvD,
                                                 float* __restrict__ hout,
                                                 int chunk_base) {
    constexpr int BM = 64, BN = 64, BK = 32;
    __shared__ double As[BK][BM + 1];  // xn (f64), k-major
    __shared__ float  Bs[BK][BN + 1];  // Wenc (f32, exact), k-major
    const int tid = threadIdx.x;
    const int m0l = blockIdx.y * BM;
    const int m0g = chunk_base + m0l;
    const int n0 = blockIdx.x * BN;
    const int tx = tid & 15, ty = tid >> 4;

    // staging indices: each thread loads 8 contiguous elems of one row
    const int r = tid >> 2;          // 0..63
    const int c = (tid & 3) * 8;     // 0,8,16,24
    const double rmu = muD[m0g + r];
    const double rin = rinvD[m0g + r];

    double acc[4][4];
#pragma unroll
    for (int i = 0; i < 4; ++i)
#pragma unroll
        for (int j = 0; j < 4; ++j) acc[i][j] = 0.0;

    for (int k0 = 0; k0 < Dn; k0 += BK) {
        {
            const float* xp = x + (size_t)(m0g + r) * Dn + k0 + c;
            float4 u0 = *(const float4*)(xp);
            float4 u1 = *(const float4*)(xp + 4);
            float4 p0 = *(const float4*)(pre_bias + k0 + c);
            float4 p1 = *(const float4*)(pre_bias + k0 + c + 4);
            As[c + 0][r] = ((double)u0.x - rmu) * rin - (double)p0.x;
            As[c + 1][r] = ((double)u0.y - rmu) * rin - (double)p0.y;
            As[c + 2][r] = ((double)u0.z - rmu) * rin - (double)p0.z;
            As[c + 3][r] = ((double)u0.w - rmu) * rin - (double)p0.w;
            As[c + 4][r] = ((double)u1.x - rmu) * rin - (double)p1.x;
            As[c + 5][r] = ((double)u1.y - rmu) * rin - (double)p1.y;
            As[c + 6][r] = ((double)u1.z - rmu) * rin - (double)p1.z;
            As[c + 7][r] = ((double)u1.w - rmu) * rin - (double)p1.w;
            const float* wp = Wenc + (size_t)(n0 + r) * Dn + k0 + c;
            float4 w0 = *(const float4*)(wp);
            float4 w1 = *(const float4*)(wp + 4);
            Bs[c + 0][r] = w0.x; Bs[c + 1][r] = w0.y;
            Bs[c + 2][r] = w0.z; Bs[c + 3][r] = w0.w;
            Bs[c + 4][r] = w1.x; Bs[c + 5][r] = w1.y;
            Bs[c + 6][r] = w1.z; Bs[c + 7][r] = w1.w;
        }
        __syncthreads();
        for (int kk = 0; kk < BK; ++kk) {
            double a[4];
            double b[4];
#pragma unroll
            for (int i = 0; i < 4; ++i) a[i] = As[kk][ty * 4 + i];
#pragma unroll
            for (int j = 0; j < 4; ++j) b[j] = (double)Bs[kk][tx * 4 + j];
#pragma unroll
            for (int i = 0; i < 4; ++i)
#pragma unroll
                for (int j = 0; j < 4; ++j)
                    acc[i][j] = fma(a[i], b[j], acc[i][j]);
        }
        __syncthreads();
    }
#pragma unroll
    for (int i = 0; i < 4; ++i) {
        const int lm = m0l + ty * 4 + i;
        float o[4];
#pragma unroll
        for (int j = 0; j < 4; ++j) {
            double vv = acc[i][j] + (double)lat_bias[n0 + tx * 4 + j];
            o[j] = fmaxf((float)vv, 0.f);
        }
        *(float4*)(hout + (size_t)lm * Hn + n0 + tx * 4) = *(float4*)&o[0];
    }
}

// Exact top-64: f32 radix threshold + f64 tie-break recompute + compaction.
__global__ __launch_bounds__(256) void k_topk(const float* __restrict__ h,
                                              const float* __restrict__ x,
                                              const float* __restrict__ Wenc,
                                              const float* __restrict__ pre_bias,
                                              const float* __restrict__ lat_bias,
                                              const double* __restrict__ muD,
                                              const double* __restrict__ rinvD,
                                              float* __restrict__ thr_out,
                                              unsigned* __restrict__ counts,
                                              int* __restrict__ idx_list,
                                              float* __restrict__ val_list,
                                              int chunk_base) {
    const int row_l = blockIdx.x;
    const int row_g = chunk_base + row_l;
    const int tid = threadIdx.x;
    const float* hr = h + (size_t)row_l * Hn;
    float v[64];
#pragma unroll
    for (int j = 0; j < 64; ++j) v[j] = hr[j * 256 + tid];

    __shared__ unsigned hist[256];
    __shared__ unsigned sh_p, sh_r;
    unsigned prefix = 0, remain = KTOP;
    for (int shift = 24; shift >= 0; shift -= 8) {
        hist[tid] = 0;
        __syncthreads();
        const unsigned mhi = (shift == 24) ? 0u : (0xFFFFFFFFu << (shift + 8));
#pragma unroll
        for (int j = 0; j < 64; ++j) {
            unsigned key = __float_as_uint(v[j]);
            if (key != 0u && (key & mhi) == prefix)
                atomicAdd(&hist[(key >> shift) & 255u], 1u);
        }
        __syncthreads();
        if (tid == 0) {
            unsigned cum = 0; int sel = 0;
            for (int b = 255; b >= 0; --b) {
                unsigned c = hist[b];
                if (cum + c >= remain) { sel = b; break; }
                cum += c;
            }
            sh_p = prefix | ((unsigned)sel << shift);
            sh_r = remain - cum;
        }
        __syncthreads();
        prefix = sh_p; remain = sh_r;
        __syncthreads();
    }
    const float thr = __uint_as_float(prefix);
    if (tid == 0) thr_out[row_g] = thr;

    // ---- exact-64 selection: classify strict-greater vs equal-at-threshold ----
    constexpr int MAXEQ = 64;
    __shared__ int s_gt, s_eq, s_ec;
    __shared__ int eqidx[MAXEQ];
    __shared__ double valD[MAXEQ];
    __shared__ int chosen[MAXEQ];
    if (tid == 0) { s_gt = 0; s_eq = 0; s_ec = 0; }
    __syncthreads();
    int gt = 0;
#pragma unroll
    for (int j = 0; j < 64; ++j) gt += (v[j] > thr) ? 1 : 0;
    if (gt) atomicAdd(&s_gt, gt);
#pragma unroll
    for (int j = 0; j < 64; ++j) {
        if (v[j] == thr) {
            atomicAdd(&s_eq, 1);
            int p = atomicAdd(&s_ec, 1);
            if (p < MAXEQ) eqidx[p] = j * 256 + tid;
        }
    }
    __syncthreads();
    const int need = KTOP - s_gt;       // >= 1 by construction
    const int ec = (s_ec < MAXEQ) ? s_ec : MAXEQ;

    if (s_eq <= need) {
        if (tid < MAXEQ) chosen[tid] = 1;   // keep whole tie group
    } else {
        // f64 recompute of tied candidates by wave 0, then pick top-`need`
        if (tid < 64) {
            const double rmu = muD[row_g];
            const double rin = rinvD[row_g];
            const float* xr = x + (size_t)row_g * Dn;
            for (int e = 0; e < ec; ++e) {
                const int feat = eqidx[e];
                const float* wr = Wenc + (size_t)feat * Dn;
                double acc = 0.0;
                for (int d = tid; d < Dn; d += 64) {
                    double xn = ((double)xr[d] - rmu) * rin - (double)pre_bias[d];
                    acc = fma(xn, (double)wr[d], acc);
                }
#pragma unroll
                for (int o = 32; o > 0; o >>= 1) acc += __shfl_down(acc, o);
                if (tid == 0) valD[e] = acc + (double)lat_bias[feat];
            }
            if (tid == 0) {
                for (int e = 0; e < ec; ++e) chosen[e] = 0;
                for (int it = 0; it < need && it < ec; ++it) {
                    int best = -1; double bv = -1e300;
                    for (int e = 0; e < ec; ++e)
                        if (!chosen[e] && valD[e] > bv) { bv = valD[e]; best = e; }
                    if (best >= 0) chosen[best] = 1;
                }
            }
        }
    }
    __syncthreads();

    // deterministic index-ordered compaction by wave 0
    if (tid < 64) {
        unsigned cnt = 0;
        for (int base = 0; base < Hn; base += 64) {
            float val = hr[base + tid];
            bool keep = (val > thr);
            if (val == thr) {
                for (int e = 0; e < ec; ++e)
                    if (eqidx[e] == base + tid) { keep = (chosen[e] != 0); break; }
            }
            unsigned long long bm = __ballot(keep);
            unsigned pre = (unsigned)__popcll(bm & ((1ull << tid) - 1ull));
            unsigned pos = cnt + pre;
            if (keep && pos < 128u) {
                idx_list[(size_t)row_g * 128 + pos] = base + tid;
                val_list[(size_t)row_g * 128 + pos] = val;
            }
            cnt += (unsigned)__popcll(bm);
        }
        if (tid == 0) counts[row_g] = cnt < 128u ? cnt : 128u;
    }
}

// sparse decoder: recon[b,:] = (sum_j val_j * WdecT[idx_j,:] + pre_bias) * std + mu
__global__ __launch_bounds__(256) void k_decoder(const float* __restrict__ WdecT,
                                                 const float* __restrict__ pre_bias,
                                                 const float* __restrict__ muF,
                                                 const float* __restrict__ stdF,
                                                 const unsigned* __restrict__ counts,
                                                 const int* __restrict__ idx_list,
                                                 const float* __restrict__ val_list,
                                                 float* __restrict__ outr) {
    const int row = blockIdx.x;
    const int tid = threadIdx.x;
    const unsigned cnt = counts[row];
    __shared__ int sidx[128];
    __shared__ float sval[128];
    if (tid < (int)cnt) {
        sidx[tid] = idx_list[(size_t)row * 128 + tid];
        sval[tid] = val_list[(size_t)row * 128 + tid];
    }
    __syncthreads();
    float a0[3] = {0.f, 0.f, 0.f};
    float a1[3] = {0.f, 0.f, 0.f};
    for (unsigned j = 0; j < cnt; ++j) {
        const float2* wr = (const float2*)(WdecT + (size_t)sidx[j] * Dn);
        const float vv = sval[j];
#pragma unroll
        for (int i = 0; i < 3; ++i) {
            float2 w = wr[tid + i * 256];
            a0[i] = fmaf(vv, w.x, a0[i]);
            a1[i] = fmaf(vv, w.y, a1[i]);
        }
    }
    const float m_ = muF[row], s_ = stdF[row];
    float2* orow = (float2*)(outr + (size_t)row * Dn);
#pragma unroll
    for (int i = 0; i < 3; ++i) {
        const int p = tid + i * 256;
        float r0 = (a0[i] + pre_bias[2 * p + 0]) * s_ + m_;
        float r1 = (a1[i] + pre_bias[2 * p + 1]) * s_ + m_;
        float2 o; o.x = r0; o.y = r1;
        orow[p] = o;
    }
}

// zero the h_sparse output region (f32), scatter kept values, accumulate stats
__global__ __launch_bounds__(256) void k_hwrite(const unsigned* __restrict__ counts,
                                                const int* __restrict__ idx_list,
                                                const float* __restrict__ val_list,
                                                float* __restrict__ outh,
                                                unsigned* __restrict__ nnz_acc,
                                                double* __restrict__ sums) {
    const int row = blockIdx.x;
    const int tid = threadIdx.x;
    const unsigned cnt = counts[row];
    float* orow = outh + (size_t)row * Hn;
    float4* orow16 = (float4*)orow;
    const float4 z = {0.f, 0.f, 0.f, 0.f};
#pragma unroll
    for (int i = 0; i < 16; ++i) orow16[tid + i * 256] = z;
    __syncthreads();
    float val = 0.f;
    if (tid < (int)cnt) {
        int idx = idx_list[(size_t)row * 128 + tid];
        val = val_list[(size_t)row * 128 + tid];
        orow[idx] = val;
    }
    float s1 = val, s2 = val * val;
    __shared__ float r1[4], r2[4];
#pragma unroll
    for (int o = 32; o > 0; o >>= 1) {
        s1 += __shfl_down(s1, o);
        s2 += __shfl_down(s2, o);
    }
    if ((tid & 63) == 0) { r1[tid >> 6] = s1; r2[tid >> 6] = s2; }
    __syncthreads();
    if (tid == 0) {
        atomicAdd(sums + 0, (double)(r1[0] + r1[1] + r1[2] + r1[3]));
        atomicAdd(sums + 1, (double)(r2[0] + r2[1] + r2[2] + r2[3]));
        atomicAdd(nnz_acc, cnt);
    }
}

__global__ void k_final(const unsigned* __restrict__ nnz,
                        const double* __restrict__ sums,
                        float* __restrict__ out3) {
    if (threadIdx.x == 0) {
        const double N = (double)Bn * (double)Hn;
        const double nz = (double)(*nnz);
        const double sparsity = (N - nz) / N;
        const double mean = sums[0] / N;
        double var = (sums[1] - N * mean * mean) / (N - 1.0);
        if (var < 0.0) var = 0.0;
        out3[0] = (float)sparsity;
        out3[1] = (float)mean;
        out3[2] = (float)sqrt(var);
    }
}

extern "C" void kernel_launch(void* const* d_in, const int* in_sizes, int n_in,
                              void* d_out, int out_size, void* d_ws, size_t ws_size,
                              hipStream_t stream) {
    const float* x        = (const float*)d_in[0];
    const float* Wenc     = (const float*)d_in[1];
    const float* Wdec     = (const float*)d_in[2];
    const float* pre_bias = (const float*)d_in[3];
    const float* lat_bias = (const float*)d_in[4];
    // d_in[5] is k (==64), hardcoded as KTOP

    char* ws = (char*)d_ws;
    float*    muF    = (float*)(ws + MU_OFF);
    float*    stdF   = (float*)(ws + STD_OFF);
    float*    thr    = (float*)(ws + THR_OFF);
    unsigned* counts = (unsigned*)(ws + CNT_OFF);
    unsigned* nnz    = (unsigned*)(ws + NNZ_OFF);
    double*   sums   = (double*)(ws + SUM_OFF);
    double*   muD    = (double*)(ws + MUD_OFF);
    double*   rinvD  = (double*)(ws + RID_OFF);
    int*      idxl   = (int*)(ws + IDX_OFF);
    float*    vall   = (float*)(ws + VAL_OFF);
    float*    hbuf   = (float*)(ws + HB_OFF);

    float* out       = (float*)d_out;
    float* out_recon = out;                                      // 8192*1536 f32
    float* out_h     = out + (size_t)Bn * Dn;                    // 8192*16384 f32
    float* out_sc    = out + (size_t)Bn * Dn + (size_t)Bn * Hn;  // 3 f32 scalars
    float* WdecT     = out_h;  // f32 W_decT staged in h region (decoder runs first)

    hipLaunchKernelGGL(k_zero, dim3(1), dim3(64), 0, stream, nnz, sums);
    hipLaunchKernelGGL(k_rowstats, dim3(Bn), dim3(256), 0, stream, x, muD, rinvD, muF, stdF);
    hipLaunchKernelGGL(k_transpose, dim3(Hn / 32, Dn / 32), dim3(256), 0, stream, Wdec, WdecT);
    for (int cb = 0; cb < Bn; cb += CHUNK) {
        hipLaunchKernelGGL(k_encoder, dim3(Hn / 64, CHUNK / 64), dim3(256), 0, stream,
                           x, Wenc, pre_bias, lat_bias, muD, rinvD, hbuf, cb);
        hipLaunchKernelGGL(k_topk, dim3(CHUNK), dim3(256), 0, stream,
                           hbuf, x, Wenc, pre_bias, lat_bias, muD, rinvD,
                           thr, counts, idxl, vall, cb);
    }
    hipLaunchKernelGGL(k_decoder, dim3(Bn), dim3(256), 0, stream,
                       WdecT, pre_bias, muF, stdF, counts, idxl, vall, out_recon);
    hipLaunchKernelGGL(k_hwrite, dim3(Bn), dim3(256), 0, stream,
                       counts, idxl, vall, out_h, nnz, sums);
    hipLaunchKernelGGL(k_final, dim3(1), dim3(64), 0, stream, nnz, sums, out_sc);
}

// Round 5
// 3499.841 us; speedup vs baseline: 3.8122x; 3.8122x over previous
//
#include <hip/hip_runtime.h>
#include <hip/hip_bf16.h>
#include <math.h>

static constexpr int Bn = 8192;
static constexpr int Dn = 1536;
static constexpr int Hn = 16384;
static constexpr int KTOP = 64;
static constexpr int KE = 4608;             // 3*Dn split-GEMM K
static constexpr double EPSD = 1e-5;

// ---- workspace byte offsets (total use ~310 MB) ----
static constexpr size_t MU_OFF  = 0;                 // float[8192]
static constexpr size_t STD_OFF = 32768;             // float[8192]
static constexpr size_t THR_OFF = 65536;             // float[8192]
static constexpr size_t CNT_OFF = 98304;             // unsigned[8192]
static constexpr size_t NNZ_OFF = 131072;            // unsigned[1]
static constexpr size_t SUM_OFF = 131200;            // double[2]
static constexpr size_t MUD_OFF = 262144;            // double[8192]
static constexpr size_t RID_OFF = 327680;            // double[8192]
static constexpr size_t IDX_OFF = (size_t)1 << 20;   // int[8192*128]
static constexpr size_t VAL_OFF = (size_t)6 << 20;   // float[8192*128]
static constexpr size_t AP_OFF  = (size_t)16 << 20;  // bf16[8192*4608]  (75.5 MB)
static constexpr size_t BP_OFF  = (size_t)96 << 20;  // bf16[16384*4608] (151 MB)
static constexpr size_t WT_OFF  = (size_t)256 << 20; // bf16[16384*1536] (50.3 MB)

typedef __attribute__((ext_vector_type(8))) short short8;
typedef __attribute__((ext_vector_type(4))) float f32x4;

static __device__ __forceinline__ unsigned short f2bf(float f) {
    __hip_bfloat16 b = __float2bfloat16(f);
    return *reinterpret_cast<unsigned short*>(&b);
}
static __device__ __forceinline__ float bf2f(unsigned short u) {
    return __uint_as_float(((unsigned)u) << 16);
}
static __device__ __forceinline__ void gload_lds16(const void* g, void* l) {
    __builtin_amdgcn_global_load_lds(
        (const __attribute__((address_space(1))) unsigned int*)g,
        (__attribute__((address_space(3))) unsigned int*)l, 16, 0, 0);
}

__global__ void k_zero(unsigned* nnz, double* sums) {
    if (threadIdx.x == 0) { *nnz = 0u; sums[0] = 0.0; sums[1] = 0.0; }
}

// f64-accurate row stats
__global__ __launch_bounds__(256) void k_rowstats(const float* __restrict__ x,
                                                  double* __restrict__ muD,
                                                  double* __restrict__ rinvD,
                                                  float* __restrict__ muF,
                                                  float* __restrict__ stdF) {
    const int row = blockIdx.x;
    const int tid = threadIdx.x;
    const float* xr = x + (size_t)row * Dn;
    float v[6];
#pragma unroll
    for (int i = 0; i < 6; ++i) v[i] = xr[tid + 256 * i];
    double s = 0.0;
#pragma unroll
    for (int i = 0; i < 6; ++i) s += (double)v[i];
    __shared__ double redD[4];
    __shared__ double smu;
#pragma unroll
    for (int o = 32; o > 0; o >>= 1) s += __shfl_down(s, o);
    if ((tid & 63) == 0) redD[tid >> 6] = s;
    __syncthreads();
    if (tid == 0) smu = (redD[0] + redD[1] + redD[2] + redD[3]) / (double)Dn;
    __syncthreads();
    const double m = smu;
    double q = 0.0;
#pragma unroll
    for (int i = 0; i < 6; ++i) { double d = (double)v[i] - m; q += d * d; }
#pragma unroll
    for (int o = 32; o > 0; o >>= 1) q += __shfl_down(q, o);
    if ((tid & 63) == 0) redD[tid >> 6] = q;
    __syncthreads();
    if (tid == 0) {
        double var = (redD[0] + redD[1] + redD[2] + redD[3]) / (double)(Dn - 1);
        double sd = sqrt(var);
        muD[row] = m;
        rinvD[row] = 1.0 / (sd + EPSD);
        muF[row] = (float)m;
        stdF[row] = (float)sd;
    }
}

// split xn-pre_bias (f64) into bf16 hi/lo; A' = [Ah | Ah | Al]
__global__ __launch_bounds__(256) void k_splitX(const float* __restrict__ x,
                                                const double* __restrict__ muD,
                                                const double* __restrict__ rinvD,
                                                const float* __restrict__ pre_bias,
                                                unsigned short* __restrict__ Ap) {
    const int row = blockIdx.x;
    const int tid = threadIdx.x;
    const double m = muD[row], ri = rinvD[row];
    const float* xr = x + (size_t)row * Dn;
    unsigned short* ar = Ap + (size_t)row * KE;
#pragma unroll
    for (int i = 0; i < 6; ++i) {
        const int d = tid + i * 256;
        double a = ((double)xr[d] - m) * ri - (double)pre_bias[d];
        unsigned short hi = f2bf((float)a);
        float hif = bf2f(hi);
        unsigned short lo = f2bf((float)(a - (double)hif));
        ar[d] = hi;
        ar[Dn + d] = hi;
        ar[2 * Dn + d] = lo;
    }
}

// split Wenc into bf16 hi/lo; B' = [Wh | Wl | Wh]
__global__ __launch_bounds__(256) void k_splitW(const float* __restrict__ Wenc,
                                                unsigned short* __restrict__ Bp) {
    const int row = blockIdx.x;
    const int tid = threadIdx.x;
    const float* wr = Wenc + (size_t)row * Dn;
    unsigned short* br = Bp + (size_t)row * KE;
#pragma unroll
    for (int i = 0; i < 6; ++i) {
        const int d = tid + i * 256;
        float w = wr[d];
        unsigned short hi = f2bf(w);
        unsigned short lo = f2bf(w - bf2f(hi));
        br[d] = hi;
        br[Dn + d] = lo;
        br[2 * Dn + d] = hi;
    }
}

// W_dec (D,H) f32 -> W_decT (H,D) bf16 in ws
__global__ __launch_bounds__(256) void k_transpose(const float* __restrict__ Wdec,
                                                   unsigned short* __restrict__ WdecT) {
    __shared__ float tile[32][33];
    const int h0 = blockIdx.x * 32;
    const int d0 = blockIdx.y * 32;
    const int tx = threadIdx.x & 31;
    const int ty = threadIdx.x >> 5;
#pragma unroll
    for (int r = 0; r < 4; ++r) {
        int d = ty + r * 8;
        tile[d][tx] = Wdec[(size_t)(d0 + d) * Hn + h0 + tx];
    }
    __syncthreads();
#pragma unroll
    for (int r = 0; r < 4; ++r) {
        int h = ty + r * 8;
        WdecT[(size_t)(h0 + h) * Dn + d0 + tx] = f2bf(tile[tx][h]);
    }
}

// bf16 MFMA GEMM: h = relu(A' * B'^T + lat_bias), M=8192 N=16384 K=4608
// 128x128 tile, 4 waves (2x2 of 64x64), BK=64, global_load_lds w16, m97-style.
__global__ __launch_bounds__(256) void k_gemm(const unsigned short* __restrict__ Ap,
                                              const unsigned short* __restrict__ Bp,
                                              const float* __restrict__ lat_bias,
                                              float* __restrict__ hout) {
    __shared__ unsigned short As[128 * 64];   // 16 KB, row = 64 bf16 = 128 B
    __shared__ unsigned short Bs[128 * 64];
    const int tid = threadIdx.x;
    const int lane = tid & 63;
    const int w = tid >> 6;
    const int wm = w >> 1, wn = w & 1;

    // block swizzle: XCD chunks of 1024, then 8x8 supertiles (8192 blocks total)
    const int nwg = (Bn / 128) * (Hn / 128);          // 64*128 = 8192
    int swz = (blockIdx.x % 8) * (nwg / 8) + blockIdx.x / 8;
    int st = swz >> 6;                                 // 128 supertiles
    int wi = swz & 63;
    int stm = st >> 4, stn = st & 15;                  // 8 x 16 supertile grid
    const int bm = stm * 8 + (wi >> 3);                // 0..63
    const int bn = stn * 8 + (wi & 7);                 // 0..127

    const int sr = tid >> 3;          // staging row-in-group 0..31
    const int sp = tid & 7;           // 16B slot 0..7
    const size_t arow0 = (size_t)(bm * 128) * KE;
    const size_t brow0 = (size_t)(bn * 128) * KE;

    f32x4 acc[4][4];
#pragma unroll
    for (int i = 0; i < 4; ++i)
#pragma unroll
        for (int j = 0; j < 4; ++j) acc[i][j] = (f32x4){0.f, 0.f, 0.f, 0.f};

    for (int k0 = 0; k0 < KE; k0 += 64) {
#pragma unroll
        for (int i = 0; i < 4; ++i) {
            gload_lds16(Ap + arow0 + (size_t)(i * 32 + sr) * KE + k0 + sp * 8,
                        (char*)As + i * 4096 + tid * 16);
            gload_lds16(Bp + brow0 + (size_t)(i * 32 + sr) * KE + k0 + sp * 8,
                        (char*)Bs + i * 4096 + tid * 16);
        }
        __syncthreads();
#pragma unroll
        for (int kk = 0; kk < 2; ++kk) {
            short8 af[4], bf[4];
#pragma unroll
            for (int f = 0; f < 4; ++f) {
                const int ar = wm * 64 + f * 16 + (lane & 15);
                af[f] = *(const short8*)((const char*)As + ar * 128 + kk * 64 + (lane >> 4) * 16);
                const int brr = wn * 64 + f * 16 + (lane & 15);
                bf[f] = *(const short8*)((const char*)Bs + brr * 128 + kk * 64 + (lane >> 4) * 16);
            }
#pragma unroll
            for (int fi = 0; fi < 4; ++fi)
#pragma unroll
                for (int fj = 0; fj < 4; ++fj)
                    acc[fi][fj] = __builtin_amdgcn_mfma_f32_16x16x32_bf16(
                        af[fi], bf[fj], acc[fi][fj], 0, 0, 0);
        }
        __syncthreads();
    }

    // epilogue: C/D map col=lane&15, row=(lane>>4)*4+reg  [m89]
    const int col = lane & 15;
    float biasv[4];
#pragma unroll
    for (int fj = 0; fj < 4; ++fj)
        biasv[fj] = lat_bias[bn * 128 + wn * 64 + fj * 16 + col];
#pragma unroll
    for (int fi = 0; fi < 4; ++fi) {
        const int gm0 = bm * 128 + wm * 64 + fi * 16 + (lane >> 4) * 4;
#pragma unroll
        for (int fj = 0; fj < 4; ++fj) {
            const int gn = bn * 128 + wn * 64 + fj * 16 + col;
#pragma unroll
            for (int r = 0; r < 4; ++r) {
                float v = acc[fi][fj][r] + biasv[fj];
                hout[(size_t)(gm0 + r) * Hn + gn] = fmaxf(v, 0.f);
            }
        }
    }
}

// exact top-64: radix threshold on approx h + f64 band refinement + compaction
__global__ __launch_bounds__(256) void k_topk(const float* __restrict__ h,
                                              const float* __restrict__ x,
                                              const float* __restrict__ Wenc,
                                              const float* __restrict__ pre_bias,
                                              const float* __restrict__ lat_bias,
                                              const double* __restrict__ muD,
                                              const double* __restrict__ rinvD,
                                              float* __restrict__ thr_out,
                                              unsigned* __restrict__ counts,
                                              int* __restrict__ idx_list,
                                              float* __restrict__ val_list) {
    const int row = blockIdx.x;
    const int tid = threadIdx.x;
    const float* hr = h + (size_t)row * Hn;
    float v[64];
#pragma unroll
    for (int j = 0; j < 64; ++j) v[j] = hr[j * 256 + tid];

    __shared__ unsigned hist[256];
    __shared__ unsigned sh_p, sh_r;
    unsigned prefix = 0, remain = KTOP;
    for (int shift = 24; shift >= 0; shift -= 8) {
        hist[tid] = 0;
        __syncthreads();
        const unsigned mhi = (shift == 24) ? 0u : (0xFFFFFFFFu << (shift + 8));
#pragma unroll
        for (int j = 0; j < 64; ++j) {
            unsigned key = __float_as_uint(v[j]);
            if (key != 0u && (key & mhi) == prefix)
                atomicAdd(&hist[(key >> shift) & 255u], 1u);
        }
        __syncthreads();
        if (tid == 0) {
            unsigned cum = 0; int sel = 0;
            for (int b = 255; b >= 0; --b) {
                unsigned c = hist[b];
                if (cum + c >= remain) { sel = b; break; }
                cum += c;
            }
            sh_p = prefix | ((unsigned)sel << shift);
            sh_r = remain - cum;
        }
        __syncthreads();
        prefix = sh_p; remain = sh_r;
        __syncthreads();
    }
    const float thr = __uint_as_float(prefix);
    if (tid == 0) thr_out[row] = thr;

    const float DELTA = 1e-3f;
    const float hi_t = thr + DELTA;
    const float lo_t = thr - DELTA;

    constexpr int MAXC = 96;
    __shared__ int s_g, s_c, s_need;
    __shared__ int cidx[MAXC];
    __shared__ double cvalD[MAXC];
    __shared__ float cref[MAXC];
    __shared__ unsigned char csel[MAXC];
    if (tid == 0) { s_g = 0; s_c = 0; }
    __syncthreads();
    int g_loc = 0;
#pragma unroll
    for (int j = 0; j < 64; ++j) {
        float val = v[j];
        if (val > hi_t) g_loc++;
        else if (val >= lo_t) {
            int p = atomicAdd(&s_c, 1);
            if (p < MAXC) cidx[p] = j * 256 + tid;
        }
    }
    if (g_loc) atomicAdd(&s_g, g_loc);
    __syncthreads();
    const int ec = (s_c < MAXC) ? s_c : MAXC;

    // f64 recompute of band candidates (wave 0)
    if (tid < 64) {
        const double rmu = muD[row];
        const double rin = rinvD[row];
        const float* xr = x + (size_t)row * Dn;
        for (int e = 0; e < ec; ++e) {
            const int feat = cidx[e];
            const float* wr = Wenc + (size_t)feat * Dn;
            double acc = 0.0;
            for (int d = tid; d < Dn; d += 64) {
                double xn = ((double)xr[d] - rmu) * rin - (double)pre_bias[d];
                acc = fma(xn, (double)wr[d], acc);
            }
#pragma unroll
            for (int o = 32; o > 0; o >>= 1) acc += __shfl_down(acc, o);
            if (tid == 0) {
                double hv = acc + (double)lat_bias[feat];
                cvalD[e] = hv;
                float hf = (float)hv;
                cref[e] = hf > 0.f ? hf : 0.f;
            }
        }
    }
    __syncthreads();
    // deterministic top-(64-g) among candidates by (value, -index)
    if (tid == 0) {
        int need = KTOP - s_g;
        s_need = need;
        for (int e = 0; e < ec; ++e) csel[e] = 0;
        for (int it = 0; it < need && it < ec; ++it) {
            int best = -1; double bv = -1e300; int bidx = 1 << 30;
            for (int e = 0; e < ec; ++e) {
                if (csel[e]) continue;
                if (cvalD[e] > bv || (cvalD[e] == bv && cidx[e] < bidx)) {
                    bv = cvalD[e]; best = e; bidx = cidx[e];
                }
            }
            if (best >= 0) csel[best] = 1;
        }
    }
    __syncthreads();

    // deterministic index-ordered compaction by wave 0
    if (tid < 64) {
        unsigned cnt = 0;
        for (int base = 0; base < Hn; base += 64) {
            const int f = base + tid;
            float val = hr[f];
            bool keep;
            float sv = val;
            if (val >= lo_t && val <= hi_t) {
                keep = false;
                for (int e = 0; e < ec; ++e)
                    if (cidx[e] == f) { keep = (csel[e] != 0); sv = cref[e]; break; }
            } else {
                keep = (val > hi_t);
            }
            unsigned long long bm = __ballot(keep);
            unsigned pre = (unsigned)__popcll(bm & ((1ull << tid) - 1ull));
            unsigned pos = cnt + pre;
            if (keep && pos < 128u) {
                idx_list[(size_t)row * 128 + pos] = f;
                val_list[(size_t)row * 128 + pos] = sv;
            }
            cnt += (unsigned)__popcll(bm);
        }
        if (tid == 0) counts[row] = cnt < 128u ? cnt : 128u;
    }
}

// sparse decoder with bf16 W_decT
__global__ __launch_bounds__(256) void k_decoder(const unsigned short* __restrict__ WdecT,
                                                 const float* __restrict__ pre_bias,
                                                 const float* __restrict__ muF,
                                                 const float* __restrict__ stdF,
                                                 const unsigned* __restrict__ counts,
                                                 const int* __restrict__ idx_list,
                                                 const float* __restrict__ val_list,
                                                 float* __restrict__ outr) {
    const int row = blockIdx.x;
    const int tid = threadIdx.x;
    const unsigned cnt = counts[row];
    __shared__ int sidx[128];
    __shared__ float sval[128];
    if (tid < (int)cnt) {
        sidx[tid] = idx_list[(size_t)row * 128 + tid];
        sval[tid] = val_list[(size_t)row * 128 + tid];
    }
    __syncthreads();
    float a0[3] = {0.f, 0.f, 0.f};
    float a1[3] = {0.f, 0.f, 0.f};
    for (unsigned j = 0; j < cnt; ++j) {
        const ushort2* wr = (const ushort2*)(WdecT + (size_t)sidx[j] * Dn);
        const float vv = sval[j];
#pragma unroll
        for (int i = 0; i < 3; ++i) {
            ushort2 wv = wr[tid + i * 256];
            a0[i] = fmaf(vv, bf2f(wv.x), a0[i]);
            a1[i] = fmaf(vv, bf2f(wv.y), a1[i]);
        }
    }
    const float m_ = muF[row], s_ = stdF[row];
    float2* orow = (float2*)(outr + (size_t)row * Dn);
#pragma unroll
    for (int i = 0; i < 3; ++i) {
        const int p = tid + i * 256;
        float2 o;
        o.x = (a0[i] + pre_bias[2 * p + 0]) * s_ + m_;
        o.y = (a1[i] + pre_bias[2 * p + 1]) * s_ + m_;
        orow[p] = o;
    }
}

// zero h_sparse region, scatter kept values, accumulate stats
__global__ __launch_bounds__(256) void k_hwrite(const unsigned* __restrict__ counts,
                                                const int* __restrict__ idx_list,
                                                const float* __restrict__ val_list,
                                                float* __restrict__ outh,
                                                unsigned* __restrict__ nnz_acc,
                                                double* __restrict__ sums) {
    const int row = blockIdx.x;
    const int tid = threadIdx.x;
    const unsigned cnt = counts[row];
    float* orow = outh + (size_t)row * Hn;
    float4* orow16 = (float4*)orow;
    const float4 z = {0.f, 0.f, 0.f, 0.f};
#pragma unroll
    for (int i = 0; i < 16; ++i) orow16[tid + i * 256] = z;
    __syncthreads();
    float val = 0.f;
    if (tid < (int)cnt) {
        int idx = idx_list[(size_t)row * 128 + tid];
        val = val_list[(size_t)row * 128 + tid];
        orow[idx] = val;
    }
    float s1 = val, s2 = val * val;
    __shared__ float r1[4], r2[4];
#pragma unroll
    for (int o = 32; o > 0; o >>= 1) {
        s1 += __shfl_down(s1, o);
        s2 += __shfl_down(s2, o);
    }
    if ((tid & 63) == 0) { r1[tid >> 6] = s1; r2[tid >> 6] = s2; }
    __syncthreads();
    if (tid == 0) {
        atomicAdd(sums + 0, (double)(r1[0] + r1[1] + r1[2] + r1[3]));
        atomicAdd(sums + 1, (double)(r2[0] + r2[1] + r2[2] + r2[3]));
        atomicAdd(nnz_acc, cnt);
    }
}

__global__ void k_final(const unsigned* __restrict__ nnz,
                        const double* __restrict__ sums,
                        float* __restrict__ out3) {
    if (threadIdx.x == 0) {
        const double N = (double)Bn * (double)Hn;
        const double nz = (double)(*nnz);
        const double sparsity = (N - nz) / N;
        const double mean = sums[0] / N;
        double var = (sums[1] - N * mean * mean) / (N - 1.0);
        if (var < 0.0) var = 0.0;
        out3[0] = (float)sparsity;
        out3[1] = (float)mean;
        out3[2] = (float)sqrt(var);
    }
}

extern "C" void kernel_launch(void* const* d_in, const int* in_sizes, int n_in,
                              void* d_out, int out_size, void* d_ws, size_t ws_size,
                              hipStream_t stream) {
    const float* x        = (const float*)d_in[0];
    const float* Wenc     = (const float*)d_in[1];
    const float* Wdec     = (const float*)d_in[2];
    const float* pre_bias = (const float*)d_in[3];
    const float* lat_bias = (const float*)d_in[4];

    char* ws = (char*)d_ws;
    float*          muF    = (float*)(ws + MU_OFF);
    float*          stdF   = (float*)(ws + STD_OFF);
    float*          thr    = (float*)(ws + THR_OFF);
    unsigned*       counts = (unsigned*)(ws + CNT_OFF);
    unsigned*       nnz    = (unsigned*)(ws + NNZ_OFF);
    double*         sums   = (double*)(ws + SUM_OFF);
    double*         muD    = (double*)(ws + MUD_OFF);
    double*         rinvD  = (double*)(ws + RID_OFF);
    int*            idxl   = (int*)(ws + IDX_OFF);
    float*          vall   = (float*)(ws + VAL_OFF);
    unsigned short* Ap     = (unsigned short*)(ws + AP_OFF);
    unsigned short* Bp     = (unsigned short*)(ws + BP_OFF);
    unsigned short* WdecT  = (unsigned short*)(ws + WT_OFF);

    float* out       = (float*)d_out;
    float* out_recon = out;
    float* out_h     = out + (size_t)Bn * Dn;
    float* out_sc    = out + (size_t)Bn * Dn + (size_t)Bn * Hn;
    float* hbuf      = out_h;   // full f32 h staged in the h_sparse output region

    hipLaunchKernelGGL(k_zero, dim3(1), dim3(64), 0, stream, nnz, sums);
    hipLaunchKernelGGL(k_rowstats, dim3(Bn), dim3(256), 0, stream, x, muD, rinvD, muF, stdF);
    hipLaunchKernelGGL(k_splitX, dim3(Bn), dim3(256), 0, stream, x, muD, rinvD, pre_bias, Ap);
    hipLaunchKernelGGL(k_splitW, dim3(Hn), dim3(256), 0, stream, Wenc, Bp);
    hipLaunchKernelGGL(k_transpose, dim3(Hn / 32, Dn / 32), dim3(256), 0, stream, Wdec, WdecT);
    hipLaunchKernelGGL(k_gemm, dim3((Bn / 128) * (Hn / 128)), dim3(256), 0, stream,
                       Ap, Bp, lat_bias, hbuf);
    hipLaunchKernelGGL(k_topk, dim3(Bn), dim3(256), 0, stream,
                       hbuf, x, Wenc, pre_bias, lat_bias, muD, rinvD,
                       thr, counts, idxl, vall);
    hipLaunchKernelGGL(k_decoder, dim3(Bn), dim3(256), 0, stream,
                       WdecT, pre_bias, muF, stdF, counts, idxl, vall, out_recon);
    hipLaunchKernelGGL(k_hwrite, dim3(Bn), dim3(256), 0, stream,
                       counts, idxl, vall, out_h, nnz, sums);
    hipLaunchKernelGGL(k_final, dim3(1), dim3(64), 0, stream, nnz, sums, out_sc);
}

// Round 6
// 3141.391 us; speedup vs baseline: 4.2472x; 1.1141x over previous
//
#include <hip/hip_runtime.h>
#include <hip/hip_bf16.h>
#include <math.h>

static constexpr int Bn = 8192;
static constexpr int Hn = 16384;
static constexpr int Dn = 1536;
static constexpr int KTOP = 64;
static constexpr int KE = 4608;             // 3*Dn split-GEMM K
static constexpr double EPSD = 1e-5;

// ---- workspace byte offsets (total use ~310 MB) ----
static constexpr size_t MU_OFF  = 0;                 // float[8192]
static constexpr size_t STD_OFF = 32768;             // float[8192]
static constexpr size_t THR_OFF = 65536;             // float[8192]
static constexpr size_t CNT_OFF = 98304;             // unsigned[8192]
static constexpr size_t NNZ_OFF = 131072;            // unsigned[1]
static constexpr size_t SUM_OFF = 131200;            // double[2]
static constexpr size_t MUD_OFF = 262144;            // double[8192]
static constexpr size_t RID_OFF = 327680;            // double[8192]
static constexpr size_t IDX_OFF = (size_t)1 << 20;   // int[8192*128]
static constexpr size_t VAL_OFF = (size_t)6 << 20;   // float[8192*128]
static constexpr size_t AP_OFF  = (size_t)16 << 20;  // bf16[8192*4608]  (75.5 MB)
static constexpr size_t BP_OFF  = (size_t)96 << 20;  // bf16[16384*4608] (151 MB)
static constexpr size_t WT_OFF  = (size_t)256 << 20; // bf16[16384*1536] (50.3 MB)

typedef __attribute__((ext_vector_type(8))) short short8;
typedef __attribute__((ext_vector_type(4))) float f32x4;

static __device__ __forceinline__ unsigned short f2bf(float f) {
    __hip_bfloat16 b = __float2bfloat16(f);
    return *reinterpret_cast<unsigned short*>(&b);
}
static __device__ __forceinline__ float bf2f(unsigned short u) {
    return __uint_as_float(((unsigned)u) << 16);
}
static __device__ __forceinline__ void gload_lds16(const void* g, void* l) {
    __builtin_amdgcn_global_load_lds(
        (const __attribute__((address_space(1))) unsigned int*)g,
        (__attribute__((address_space(3))) unsigned int*)l, 16, 0, 0);
}

__global__ void k_zero(unsigned* nnz, double* sums) {
    if (threadIdx.x == 0) { *nnz = 0u; sums[0] = 0.0; sums[1] = 0.0; }
}

// f64-accurate row stats
__global__ __launch_bounds__(256) void k_rowstats(const float* __restrict__ x,
                                                  double* __restrict__ muD,
                                                  double* __restrict__ rinvD,
                                                  float* __restrict__ muF,
                                                  float* __restrict__ stdF) {
    const int row = blockIdx.x;
    const int tid = threadIdx.x;
    const float* xr = x + (size_t)row * Dn;
    float v[6];
#pragma unroll
    for (int i = 0; i < 6; ++i) v[i] = xr[tid + 256 * i];
    double s = 0.0;
#pragma unroll
    for (int i = 0; i < 6; ++i) s += (double)v[i];
    __shared__ double redD[4];
    __shared__ double smu;
#pragma unroll
    for (int o = 32; o > 0; o >>= 1) s += __shfl_down(s, o);
    if ((tid & 63) == 0) redD[tid >> 6] = s;
    __syncthreads();
    if (tid == 0) smu = (redD[0] + redD[1] + redD[2] + redD[3]) / (double)Dn;
    __syncthreads();
    const double m = smu;
    double q = 0.0;
#pragma unroll
    for (int i = 0; i < 6; ++i) { double d = (double)v[i] - m; q += d * d; }
#pragma unroll
    for (int o = 32; o > 0; o >>= 1) q += __shfl_down(q, o);
    if ((tid & 63) == 0) redD[tid >> 6] = q;
    __syncthreads();
    if (tid == 0) {
        double var = (redD[0] + redD[1] + redD[2] + redD[3]) / (double)(Dn - 1);
        double sd = sqrt(var);
        muD[row] = m;
        rinvD[row] = 1.0 / (sd + EPSD);
        muF[row] = (float)m;
        stdF[row] = (float)sd;
    }
}

// split xn-pre_bias (f64) into bf16 hi/lo; A' = [Ah | Ah | Al]
__global__ __launch_bounds__(256) void k_splitX(const float* __restrict__ x,
                                                const double* __restrict__ muD,
                                                const double* __restrict__ rinvD,
                                                const float* __restrict__ pre_bias,
                                                unsigned short* __restrict__ Ap) {
    const int row = blockIdx.x;
    const int tid = threadIdx.x;
    const double m = muD[row], ri = rinvD[row];
    const float* xr = x + (size_t)row * Dn;
    unsigned short* ar = Ap + (size_t)row * KE;
#pragma unroll
    for (int i = 0; i < 6; ++i) {
        const int d = tid + i * 256;
        double a = ((double)xr[d] - m) * ri - (double)pre_bias[d];
        unsigned short hi = f2bf((float)a);
        float hif = bf2f(hi);
        unsigned short lo = f2bf((float)(a - (double)hif));
        ar[d] = hi;
        ar[Dn + d] = hi;
        ar[2 * Dn + d] = lo;
    }
}

// split Wenc into bf16 hi/lo; B' = [Wh | Wl | Wh]
__global__ __launch_bounds__(256) void k_splitW(const float* __restrict__ Wenc,
                                                unsigned short* __restrict__ Bp) {
    const int row = blockIdx.x;
    const int tid = threadIdx.x;
    const float* wr = Wenc + (size_t)row * Dn;
    unsigned short* br = Bp + (size_t)row * KE;
#pragma unroll
    for (int i = 0; i < 6; ++i) {
        const int d = tid + i * 256;
        float w = wr[d];
        unsigned short hi = f2bf(w);
        unsigned short lo = f2bf(w - bf2f(hi));
        br[d] = hi;
        br[Dn + d] = lo;
        br[2 * Dn + d] = hi;
    }
}

// W_dec (D,H) f32 -> W_decT (H,D) bf16 in ws
__global__ __launch_bounds__(256) void k_transpose(const float* __restrict__ Wdec,
                                                   unsigned short* __restrict__ WdecT) {
    __shared__ float tile[32][33];
    const int h0 = blockIdx.x * 32;
    const int d0 = blockIdx.y * 32;
    const int tx = threadIdx.x & 31;
    const int ty = threadIdx.x >> 5;
#pragma unroll
    for (int r = 0; r < 4; ++r) {
        int d = ty + r * 8;
        tile[d][tx] = Wdec[(size_t)(d0 + d) * Hn + h0 + tx];
    }
    __syncthreads();
#pragma unroll
    for (int r = 0; r < 4; ++r) {
        int h = ty + r * 8;
        WdecT[(size_t)(h0 + h) * Dn + d0 + tx] = f2bf(tile[tx][h]);
    }
}

// bf16 MFMA GEMM: h = relu(A' * B'^T + lat_bias), M=8192 N=16384 K=4608
// 128x128 tile, 4 waves, BK=64 (128-B LDS rows). XOR bank-swizzle:
// LDS(row, slot16) holds global(row, slot16 ^ (row&7)); the read applies the
// same XOR -> slots distinct across any 8 consecutive rows -> conflict-free.
__global__ __launch_bounds__(256) void k_gemm(const unsigned short* __restrict__ Ap,
                                              const unsigned short* __restrict__ Bp,
                                              const float* __restrict__ lat_bias,
                                              float* __restrict__ hout) {
    __shared__ unsigned short As[128 * 64];   // 16 KB, row = 64 bf16 = 128 B
    __shared__ unsigned short Bs[128 * 64];
    const int tid = threadIdx.x;
    const int lane = tid & 63;
    const int w = tid >> 6;
    const int wm = w >> 1, wn = w & 1;

    // block swizzle: XCD chunks, then 8x8 supertiles (8192 blocks total)
    const int nwg = (Bn / 128) * (Hn / 128);          // 8192
    int swz = (blockIdx.x % 8) * (nwg / 8) + blockIdx.x / 8;
    int st = swz >> 6;
    int wi = swz & 63;
    int stm = st >> 4, stn = st & 15;
    const int bm = stm * 8 + (wi >> 3);               // 0..63
    const int bn = stn * 8 + (wi & 7);                // 0..127

    const int sr = tid >> 3;          // staging row-in-group 0..31
    const int sp = tid & 7;           // 16B slot 0..7
    const int ssl = sp ^ (sr & 7);    // source slot (inverse swizzle)
    const size_t arow0 = (size_t)(bm * 128) * KE;
    const size_t brow0 = (size_t)(bn * 128) * KE;

    f32x4 acc[4][4];
#pragma unroll
    for (int i = 0; i < 4; ++i)
#pragma unroll
        for (int j = 0; j < 4; ++j) acc[i][j] = (f32x4){0.f, 0.f, 0.f, 0.f};

    for (int k0 = 0; k0 < KE; k0 += 64) {
#pragma unroll
        for (int i = 0; i < 4; ++i) {
            gload_lds16(Ap + arow0 + (size_t)(i * 32 + sr) * KE + k0 + ssl * 8,
                        (char*)As + i * 4096 + tid * 16);
            gload_lds16(Bp + brow0 + (size_t)(i * 32 + sr) * KE + k0 + ssl * 8,
                        (char*)Bs + i * 4096 + tid * 16);
        }
        __syncthreads();
#pragma unroll
        for (int kk = 0; kk < 2; ++kk) {
            short8 af[4], bf[4];
#pragma unroll
            for (int f = 0; f < 4; ++f) {
                const int ar = wm * 64 + f * 16 + (lane & 15);
                const int aslot = (kk * 4 + (lane >> 4)) ^ (ar & 7);
                af[f] = *(const short8*)((const char*)As + ar * 128 + aslot * 16);
                const int brr = wn * 64 + f * 16 + (lane & 15);
                const int bslot = (kk * 4 + (lane >> 4)) ^ (brr & 7);
                bf[f] = *(const short8*)((const char*)Bs + brr * 128 + bslot * 16);
            }
#pragma unroll
            for (int fi = 0; fi < 4; ++fi)
#pragma unroll
                for (int fj = 0; fj < 4; ++fj)
                    acc[fi][fj] = __builtin_amdgcn_mfma_f32_16x16x32_bf16(
                        af[fi], bf[fj], acc[fi][fj], 0, 0, 0);
        }
        __syncthreads();
    }

    // epilogue: C/D map col=lane&15, row=(lane>>4)*4+reg  [m89]
    const int col = lane & 15;
    float biasv[4];
#pragma unroll
    for (int fj = 0; fj < 4; ++fj)
        biasv[fj] = lat_bias[bn * 128 + wn * 64 + fj * 16 + col];
#pragma unroll
    for (int fi = 0; fi < 4; ++fi) {
        const int gm0 = bm * 128 + wm * 64 + fi * 16 + (lane >> 4) * 4;
#pragma unroll
        for (int fj = 0; fj < 4; ++fj) {
            const int gn = bn * 128 + wn * 64 + fj * 16 + col;
#pragma unroll
            for (int r = 0; r < 4; ++r) {
                float v = acc[fi][fj][r] + biasv[fj];
                hout[(size_t)(gm0 + r) * Hn + gn] = fmaxf(v, 0.f);
            }
        }
    }
}

// exact top-64: radix threshold on approx h + f64 band refinement + compaction
__global__ __launch_bounds__(256) void k_topk(const float* __restrict__ h,
                                              const float* __restrict__ x,
                                              const float* __restrict__ Wenc,
                                              const float* __restrict__ pre_bias,
                                              const float* __restrict__ lat_bias,
                                              const double* __restrict__ muD,
                                              const double* __restrict__ rinvD,
                                              float* __restrict__ thr_out,
                                              unsigned* __restrict__ counts,
                                              int* __restrict__ idx_list,
                                              float* __restrict__ val_list) {
    const int row = blockIdx.x;
    const int tid = threadIdx.x;
    const float* hr = h + (size_t)row * Hn;
    float v[64];
#pragma unroll
    for (int j = 0; j < 64; ++j) v[j] = hr[j * 256 + tid];

    __shared__ unsigned hist[256];
    __shared__ unsigned sh_p, sh_r;
    unsigned prefix = 0, remain = KTOP;
    for (int shift = 24; shift >= 0; shift -= 8) {
        hist[tid] = 0;
        __syncthreads();
        const unsigned mhi = (shift == 24) ? 0u : (0xFFFFFFFFu << (shift + 8));
#pragma unroll
        for (int j = 0; j < 64; ++j) {
            unsigned key = __float_as_uint(v[j]);
            if (key != 0u && (key & mhi) == prefix)
                atomicAdd(&hist[(key >> shift) & 255u], 1u);
        }
        __syncthreads();
        if (tid == 0) {
            unsigned cum = 0; int sel = 0;
            for (int b = 255; b >= 0; --b) {
                unsigned c = hist[b];
                if (cum + c >= remain) { sel = b; break; }
                cum += c;
            }
            sh_p = prefix | ((unsigned)sel << shift);
            sh_r = remain - cum;
        }
        __syncthreads();
        prefix = sh_p; remain = sh_r;
        __syncthreads();
    }
    const float thr = __uint_as_float(prefix);
    if (tid == 0) thr_out[row] = thr;

    const float DELTA = 1e-3f;
    const float hi_t = thr + DELTA;
    const float lo_t = thr - DELTA;

    constexpr int MAXC = 96;
    __shared__ int s_g, s_c, s_need;
    __shared__ int cidx[MAXC];
    __shared__ double cvalD[MAXC];
    __shared__ float cref[MAXC];
    __shared__ unsigned char csel[MAXC];
    if (tid == 0) { s_g = 0; s_c = 0; }
    __syncthreads();
    int g_loc = 0;
#pragma unroll
    for (int j = 0; j < 64; ++j) {
        float val = v[j];
        if (val > hi_t) g_loc++;
        else if (val >= lo_t) {
            int p = atomicAdd(&s_c, 1);
            if (p < MAXC) cidx[p] = j * 256 + tid;
        }
    }
    if (g_loc) atomicAdd(&s_g, g_loc);
    __syncthreads();
    const int ec = (s_c < MAXC) ? s_c : MAXC;

    // f64 recompute of band candidates (wave 0)
    if (tid < 64) {
        const double rmu = muD[row];
        const double rin = rinvD[row];
        const float* xr = x + (size_t)row * Dn;
        for (int e = 0; e < ec; ++e) {
            const int feat = cidx[e];
            const float* wr = Wenc + (size_t)feat * Dn;
            double acc = 0.0;
            for (int d = tid; d < Dn; d += 64) {
                double xn = ((double)xr[d] - rmu) * rin - (double)pre_bias[d];
                acc = fma(xn, (double)wr[d], acc);
            }
#pragma unroll
            for (int o = 32; o > 0; o >>= 1) acc += __shfl_down(acc, o);
            if (tid == 0) {
                double hv = acc + (double)lat_bias[feat];
                cvalD[e] = hv;
                float hf = (float)hv;
                cref[e] = hf > 0.f ? hf : 0.f;
            }
        }
    }
    __syncthreads();
    // deterministic top-(64-g) among candidates by (value, -index)
    if (tid == 0) {
        int need = KTOP - s_g;
        s_need = need;
        for (int e = 0; e < ec; ++e) csel[e] = 0;
        for (int it = 0; it < need && it < ec; ++it) {
            int best = -1; double bv = -1e300; int bidx = 1 << 30;
            for (int e = 0; e < ec; ++e) {
                if (csel[e]) continue;
                if (cvalD[e] > bv || (cvalD[e] == bv && cidx[e] < bidx)) {
                    bv = cvalD[e]; best = e; bidx = cidx[e];
                }
            }
            if (best >= 0) csel[best] = 1;
        }
    }
    __syncthreads();

    // deterministic index-ordered compaction by wave 0
    if (tid < 64) {
        unsigned cnt = 0;
        for (int base = 0; base < Hn; base += 64) {
            const int f = base + tid;
            float val = hr[f];
            bool keep;
            float sv = val;
            if (val >= lo_t && val <= hi_t) {
                keep = false;
                for (int e = 0; e < ec; ++e)
                    if (cidx[e] == f) { keep = (csel[e] != 0); sv = cref[e]; break; }
            } else {
                keep = (val > hi_t);
            }
            unsigned long long bm = __ballot(keep);
            unsigned pre = (unsigned)__popcll(bm & ((1ull << tid) - 1ull));
            unsigned pos = cnt + pre;
            if (keep && pos < 128u) {
                idx_list[(size_t)row * 128 + pos] = f;
                val_list[(size_t)row * 128 + pos] = sv;
            }
            cnt += (unsigned)__popcll(bm);
        }
        if (tid == 0) counts[row] = cnt < 128u ? cnt : 128u;
    }
}

// sparse decoder with bf16 W_decT
__global__ __launch_bounds__(256) void k_decoder(const unsigned short* __restrict__ WdecT,
                                                 const float* __restrict__ pre_bias,
                                                 const float* __restrict__ muF,
                                                 const float* __restrict__ stdF,
                                                 const unsigned* __restrict__ counts,
                                                 const int* __restrict__ idx_list,
                                                 const float* __restrict__ val_list,
                                                 float* __restrict__ outr) {
    const int row = blockIdx.x;
    const int tid = threadIdx.x;
    const unsigned cnt = counts[row];
    __shared__ int sidx[128];
    __shared__ float sval[128];
    if (tid < (int)cnt) {
        sidx[tid] = idx_list[(size_t)row * 128 + tid];
        sval[tid] = val_list[(size_t)row * 128 + tid];
    }
    __syncthreads();
    float a0[3] = {0.f, 0.f, 0.f};
    float a1[3] = {0.f, 0.f, 0.f};
    for (unsigned j = 0; j < cnt; ++j) {
        const ushort2* wr = (const ushort2*)(WdecT + (size_t)sidx[j] * Dn);
        const float vv = sval[j];
#pragma unroll
        for (int i = 0; i < 3; ++i) {
            ushort2 wv = wr[tid + i * 256];
            a0[i] = fmaf(vv, bf2f(wv.x), a0[i]);
            a1[i] = fmaf(vv, bf2f(wv.y), a1[i]);
        }
    }
    const float m_ = muF[row], s_ = stdF[row];
    float2* orow = (float2*)(outr + (size_t)row * Dn);
#pragma unroll
    for (int i = 0; i < 3; ++i) {
        const int p = tid + i * 256;
        float2 o;
        o.x = (a0[i] + pre_bias[2 * p + 0]) * s_ + m_;
        o.y = (a1[i] + pre_bias[2 * p + 1]) * s_ + m_;
        orow[p] = o;
    }
}

// zero h_sparse region, scatter kept values, accumulate stats
__global__ __launch_bounds__(256) void k_hwrite(const unsigned* __restrict__ counts,
                                                const int* __restrict__ idx_list,
                                                const float* __restrict__ val_list,
                                                float* __restrict__ outh,
                                                unsigned* __restrict__ nnz_acc,
                                                double* __restrict__ sums) {
    const int row = blockIdx.x;
    const int tid = threadIdx.x;
    const unsigned cnt = counts[row];
    float* orow = outh + (size_t)row * Hn;
    float4* orow16 = (float4*)orow;
    const float4 z = {0.f, 0.f, 0.f, 0.f};
#pragma unroll
    for (int i = 0; i < 16; ++i) orow16[tid + i * 256] = z;
    __syncthreads();
    float val = 0.f;
    if (tid < (int)cnt) {
        int idx = idx_list[(size_t)row * 128 + tid];
        val = val_list[(size_t)row * 128 + tid];
        orow[idx] = val;
    }
    float s1 = val, s2 = val * val;
    __shared__ float r1[4], r2[4];
#pragma unroll
    for (int o = 32; o > 0; o >>= 1) {
        s1 += __shfl_down(s1, o);
        s2 += __shfl_down(s2, o);
    }
    if ((tid & 63) == 0) { r1[tid >> 6] = s1; r2[tid >> 6] = s2; }
    __syncthreads();
    if (tid == 0) {
        atomicAdd(sums + 0, (double)(r1[0] + r1[1] + r1[2] + r1[3]));
        atomicAdd(sums + 1, (double)(r2[0] + r2[1] + r2[2] + r2[3]));
        atomicAdd(nnz_acc, cnt);
    }
}

__global__ void k_final(const unsigned* __restrict__ nnz,
                        const double* __restrict__ sums,
                        float* __restrict__ out3) {
    if (threadIdx.x == 0) {
        const double N = (double)Bn * (double)Hn;
        const double nz = (double)(*nnz);
        const double sparsity = (N - nz) / N;
        const double mean = sums[0] / N;
        double var = (sums[1] - N * mean * mean) / (N - 1.0);
        if (var < 0.0) var = 0.0;
        out3[0] = (float)sparsity;
        out3[1] = (float)mean;
        out3[2] = (float)sqrt(var);
    }
}

extern "C" void kernel_launch(void* const* d_in, const int* in_sizes, int n_in,
                              void* d_out, int out_size, void* d_ws, size_t ws_size,
                              hipStream_t stream) {
    const float* x        = (const float*)d_in[0];
    const float* Wenc     = (const float*)d_in[1];
    const float* Wdec     = (const float*)d_in[2];
    const float* pre_bias = (const float*)d_in[3];
    const float* lat_bias = (const float*)d_in[4];

    char* ws = (char*)d_ws;
    float*          muF    = (float*)(ws + MU_OFF);
    float*          stdF   = (float*)(ws + STD_OFF);
    float*          thr    = (float*)(ws + THR_OFF);
    unsigned*       counts = (unsigned*)(ws + CNT_OFF);
    unsigned*       nnz    = (unsigned*)(ws + NNZ_OFF);
    double*         sums   = (double*)(ws + SUM_OFF);
    double*         muD    = (double*)(ws + MUD_OFF);
    double*         rinvD  = (double*)(ws + RID_OFF);
    int*            idxl   = (int*)(ws + IDX_OFF);
    float*          vall   = (float*)(ws + VAL_OFF);
    unsigned short* Ap     = (unsigned short*)(ws + AP_OFF);
    unsigned short* Bp     = (unsigned short*)(ws + BP_OFF);
    unsigned short* WdecT  = (unsigned short*)(ws + WT_OFF);

    float* out       = (float*)d_out;
    float* out_recon = out;
    float* out_h     = out + (size_t)Bn * Dn;
    float* out_sc    = out + (size_t)Bn * Dn + (size_t)Bn * Hn;
    float* hbuf      = out_h;   // full f32 h staged in the h_sparse output region

    hipLaunchKernelGGL(k_zero, dim3(1), dim3(64), 0, stream, nnz, sums);
    hipLaunchKernelGGL(k_rowstats, dim3(Bn), dim3(256), 0, stream, x, muD, rinvD, muF, stdF);
    hipLaunchKernelGGL(k_splitX, dim3(Bn), dim3(256), 0, stream, x, muD, rinvD, pre_bias, Ap);
    hipLaunchKernelGGL(k_splitW, dim3(Hn), dim3(256), 0, stream, Wenc, Bp);
    hipLaunchKernelGGL(k_transpose, dim3(Hn / 32, Dn / 32), dim3(256), 0, stream, Wdec, WdecT);
    hipLaunchKernelGGL(k_gemm, dim3((Bn / 128) * (Hn / 128)), dim3(256), 0, stream,
                       Ap, Bp, lat_bias, hbuf);
    hipLaunchKernelGGL(k_topk, dim3(Bn), dim3(256), 0, stream,
                       hbuf, x, Wenc, pre_bias, lat_bias, muD, rinvD,
                       thr, counts, idxl, vall);
    hipLaunchKernelGGL(k_decoder, dim3(Bn), dim3(256), 0, stream,
                       WdecT, pre_bias, muF, stdF, counts, idxl, vall, out_recon);
    hipLaunchKernelGGL(k_hwrite, dim3(Bn), dim3(256), 0, stream,
                       counts, idxl, vall, out_h, nnz, sums);
    hipLaunchKernelGGL(k_final, dim3(1), dim3(64), 0, stream, nnz, sums, out_sc);
}